// Round 15
// baseline (156.547 us; speedup 1.0000x reference)
//
#include <hip/hip_runtime.h>

typedef float f32x4 __attribute__((ext_vector_type(4)));
typedef short s16x8 __attribute__((ext_vector_type(8)));
typedef unsigned short ushort_t;

#define L_TOT 1360
#define BROWS 5440   // 4 * 1360
#define DM    1024

__device__ __forceinline__ float b2f(ushort_t u){
  union { unsigned int u; float f; } v; v.u = ((unsigned int)u) << 16; return v.f;
}
__device__ __forceinline__ ushort_t f2bf(float f){
  union { float f; unsigned int u; } v; v.f = f;
  unsigned int u = v.u;
  unsigned int r = u + 0x7fffu + ((u >> 16) & 1u);
  return (ushort_t)(r >> 16);
}
__device__ __forceinline__ unsigned cvtpk(float lo, float hi){
  unsigned r; asm("v_cvt_pk_bf16_f32 %0, %1, %2" : "=v"(r) : "v"(lo), "v"(hi)); return r;
}
__device__ __forceinline__ void gload16(const ushort_t* g, ushort_t* l){
  __builtin_amdgcn_global_load_lds(
      (const __attribute__((address_space(1))) unsigned int*)g,
      (__attribute__((address_space(3))) unsigned int*)l, 16, 0, 0);
}

#define FENCE_VM12 asm volatile("s_waitcnt vmcnt(12)" ::: "memory")
#define FENCE_VM8  asm volatile("s_waitcnt vmcnt(8)" ::: "memory")
#define FENCE_VM4  asm volatile("s_waitcnt vmcnt(4)" ::: "memory")
#define FENCE_VM3  asm volatile("s_waitcnt vmcnt(3)" ::: "memory")
#define FENCE_VM0  asm volatile("s_waitcnt vmcnt(0)" ::: "memory")
#define BAR        __builtin_amdgcn_s_barrier()

// ---------------------------------------------------------------------------
// sigma k-layout: within each 32-k block, quads stored [q0 q4 q1 q5 q2 q6 q3 q7]
// (16B chunk c = MFMA fragment k-set {4c+i} u {16+4c+i}); LDS slot-XOR involution
// slot s of row r holds chunk s ^ ((r>>1)&3). Verified r4: 0 bank conflicts.
// ---------------------------------------------------------------------------

// ---------------------------------------------------------------- fused prep (r12 version)
__global__ __launch_bounds__(256) void prep_kernel(const float* __restrict__ x,
    const float* __restrict__ Wq, const float* __restrict__ Wk,
    const float* __restrict__ Wv, const float* __restrict__ Wfc,
    const float* __restrict__ gamma, const float* __restrict__ beta,
    float* __restrict__ mu, float* __restrict__ rs, ushort_t* __restrict__ xbf,
    float* __restrict__ cg, float* __restrict__ cb,
    ushort_t* __restrict__ Wqkv_t, ushort_t* __restrict__ Wfc_t){
  __shared__ float smem[64 * 68];
  const int bid = blockIdx.x;
  const int t = threadIdx.x;

  if (bid < BROWS){
    const int row = bid;
    f32x4 v = *reinterpret_cast<const f32x4*>(x + (size_t)row * DM + t * 4);
    {
      const int off = 32 * (t >> 3) + 8 * (t & 3) + 4 * ((t >> 2) & 1);
      uint2 o; o.x = cvtpk(v.x, v.y); o.y = cvtpk(v.z, v.w);
      *reinterpret_cast<uint2*>(xbf + (size_t)row * DM + off) = o;
    }
    float s  = v.x + v.y + v.z + v.w;
    float s2 = v.x*v.x + v.y*v.y + v.z*v.z + v.w*v.w;
    #pragma unroll
    for (int off = 32; off; off >>= 1){ s += __shfl_xor(s, off); s2 += __shfl_xor(s2, off); }
    const int wid = t >> 6, lane = t & 63;
    if (lane == 0){ smem[wid] = s; smem[4 + wid] = s2; }
    __syncthreads();
    if (t == 0){
      s  = smem[0] + smem[1] + smem[2] + smem[3];
      s2 = smem[4] + smem[5] + smem[6] + smem[7];
      const float m = s * (1.0f / DM);
      const float var = s2 * (1.0f / DM) - m * m;
      mu[row] = m;
      rs[row] = rsqrtf(var + 1e-6f);
    }
  } else if (bid < BROWS + 64){
    float* shg = smem;
    float* shb = smem + 16 * 17;
    const int c = t & 15;
    const int kq = t >> 4;
    const int col = (bid - BROWS) * 16 + c;
    float sg = 0.f, sb = 0.f;
    for (int k = kq * 64; k < kq * 64 + 64; k++){
      const float w = Wq[(size_t)k * DM + col];
      sg += gamma[k] * w;
      sb += beta[k] * w;
    }
    shg[kq * 17 + c] = sg; shb[kq * 17 + c] = sb;
    __syncthreads();
    if (kq == 0){
      float tg = 0.f, tb = 0.f;
      #pragma unroll
      for (int q2 = 0; q2 < 16; q2++){ tg += shg[q2 * 17 + c]; tb += shb[q2 * 17 + c]; }
      cg[col] = tg; cb[col] = tb;
    }
  } else {
    const int q2 = bid - BROWS - 64;
    const int z = q2 >> 8, rem = q2 & 255;
    const int kx = rem & 15, ny = rem >> 4;
    const float* W = (z == 0) ? Wq : (z == 1) ? Wk : (z == 2) ? Wv : Wfc;
    ushort_t* D = (z == 3) ? Wfc_t : (Wqkv_t + (size_t)z * DM * DM);
    const int k0 = kx * 64, n0 = ny * 64;
    const int tr = t >> 4, tc = t & 15;
    #pragma unroll
    for (int it = 0; it < 4; it++){
      const int r = tr + it * 16;
      f32x4 v = *reinterpret_cast<const f32x4*>(W + (size_t)(k0 + r) * DM + n0 + tc * 4);
      if (z == 0){ const float g = gamma[k0 + r]; v.x *= g; v.y *= g; v.z *= g; v.w *= g; }
      *reinterpret_cast<f32x4*>(&smem[r * 68 + tc * 4]) = v;
    }
    __syncthreads();
    const int soff = k0 + 32 * (tc >> 3) + 8 * (tc & 3) + 4 * ((tc >> 2) & 1);
    #pragma unroll
    for (int it = 0; it < 4; it++){
      const int rn = tr + it * 16;
      float a = smem[(tc*4+0) * 68 + rn], b = smem[(tc*4+1) * 68 + rn];
      float c = smem[(tc*4+2) * 68 + rn], d = smem[(tc*4+3) * 68 + rn];
      uint2 w; w.x = cvtpk(a, b); w.y = cvtpk(c, d);
      *reinterpret_cast<uint2*>(D + (size_t)(n0 + rn) * DM + soff) = w;
    }
  }
}

// ---------------------------------------------------------------- fused QKV GEMM (depth-4)
// 128x128 tile, BK=32, 4 waves (2m x 2n), wave-tile 64x64 (4x4 frags, 16 MFMA/iter).
// 5 LDS buffers x 16KB = 80KB -> exactly 2 blocks/CU (TLP) AND depth-4 prefetch
// slack (~4 K-steps ~ 2400cy) to cover loaded global latency (~2000-3000cy).
// Ledger (4 gloads/thread/iter, FIFO): steady fence vmcnt(12) = 3 newest stages
// in flight, stage(kt+1) landed. Drain: vmcnt(8), vmcnt(4)... wait, see tail.
// Grid 1032 = 8 XCDs x 129 (bijective); ragged m-row ty=42 handled via miN.
__global__ __launch_bounds__(256, 2) void qkv_gemm(const ushort_t* __restrict__ A,
    const ushort_t* __restrict__ Bt, ushort_t* __restrict__ Qb, ushort_t* __restrict__ KVb,
    const float* __restrict__ cg, const float* __restrict__ cb,
    const float* __restrict__ mu, const float* __restrict__ rs){
  __shared__ __align__(16) ushort_t As[5][128 * 32];   // 40 KB
  __shared__ __align__(16) ushort_t Bs[5][128 * 32];   // 40 KB
  const int tid = threadIdx.x;
  const int w = tid >> 6, lane = tid & 63;
  const int l15 = lane & 15, lg = lane >> 4;
  const int wr = w >> 1, wc = w & 1;

  const int idx = (int)blockIdx.x;
  const int wg = (idx & 7) * 129 + (idx >> 3);          // 1032 = 8*129, bijective
  const int ty = wg / 24, tx = wg % 24;
  const int m0 = ty * 128, n0 = tx * 128;

  // staging (r4-proven): lane = (rch = row-in-16, slot); source chunk = slot^((r>>1)&3)
  const int rch = lane >> 2, slot = lane & 3;
  const int gch = slot ^ ((rch >> 1) & 3);
  int ar0 = m0 + w * 32 + rch;      if (ar0 > BROWS - 1) ar0 = BROWS - 1;
  int ar1 = m0 + w * 32 + 16 + rch; if (ar1 > BROWS - 1) ar1 = BROWS - 1;
  const ushort_t* a_src0 = A  + (size_t)ar0 * DM + gch * 8;
  const ushort_t* a_src1 = A  + (size_t)ar1 * DM + gch * 8;
  const ushort_t* b_src0 = Bt + (size_t)(n0 + w * 32      + rch) * DM + gch * 8;
  const ushort_t* b_src1 = Bt + (size_t)(n0 + w * 32 + 16 + rch) * DM + gch * 8;

  #define STAGE(P, T) do { \
    gload16(a_src0 + (T) * 32, &As[P][(w * 32     ) * 32]); \
    gload16(a_src1 + (T) * 32, &As[P][(w * 32 + 16) * 32]); \
    gload16(b_src0 + (T) * 32, &Bs[P][(w * 32     ) * 32]); \
    gload16(b_src1 + (T) * 32, &Bs[P][(w * 32 + 16) * 32]); \
  } while(0)

  const int fs = lg ^ ((l15 >> 1) & 3);   // read-slot involution (0-conflict, r4)

  int miN = (BROWS - m0 - wr * 64 + 15) >> 4;
  if (miN > 4) miN = 4;
  if (miN < 0) miN = 0;

  f32x4 acc[4][4];
  #pragma unroll
  for (int a = 0; a < 4; a++)
    #pragma unroll
    for (int b = 0; b < 4; b++) acc[a][b] = (f32x4){0.f,0.f,0.f,0.f};

  // prologue: stages 0..3 (16 loads); fence so stage0 landed (12 newest may fly)
  STAGE(0, 0);
  STAGE(1, 1);
  STAGE(2, 2);
  STAGE(3, 3);
  FENCE_VM12;
  BAR;

  int p = 0, p4 = 4;
  for (int kt = 0; kt < 32; ++kt){
    if (kt <= 27) STAGE(p4, kt + 4);

    s16x8 af[4], bf[4];
    #pragma unroll
    for (int ni = 0; ni < 4; ni++)
      bf[ni] = *reinterpret_cast<const s16x8*>(&Bs[p][(wc*64 + ni*16 + l15) * 32 + fs * 8]);
    #pragma unroll
    for (int mi = 0; mi < 4; mi++)
      if (mi < miN)
        af[mi] = *reinterpret_cast<const s16x8*>(&As[p][(wr*64 + mi*16 + l15) * 32 + fs * 8]);

    #pragma unroll
    for (int mi = 0; mi < 4; mi++)
      if (mi < miN)
        #pragma unroll
        for (int ni = 0; ni < 4; ni++)
          acc[mi][ni] = __builtin_amdgcn_mfma_f32_16x16x32_bf16(af[mi], bf[ni], acc[mi][ni], 0, 0, 0);

    if (kt < 31){
      // fence: stage(kt+1) must have landed before next iter reads it.
      if (kt <= 27)      FENCE_VM12;   // outstanding: kt+2..kt+4 (12 loads)
      else if (kt == 28) FENCE_VM8;    // outstanding: 30,31 (8)
      else if (kt == 29) FENCE_VM4;    // outstanding: 31 (4)
      else               FENCE_VM0;    // kt==30: drain
      BAR;
    }
    p  = (p  == 4) ? 0 : p  + 1;
    p4 = (p4 == 4) ? 0 : p4 + 1;
  }
  #undef STAGE

  // epilogue: tx<8 -> Q (LN fold), 8-16 -> K, 16-24 -> V
  const bool isQ = (tx < 8);
  ushort_t* outp; int ostride, col0;
  if (tx < 8)      { outp = Qb;  ostride = 1024; col0 = tx * 128; }
  else if (tx < 16){ outp = KVb; ostride = 2048; col0 = (tx - 8) * 128; }
  else             { outp = KVb; ostride = 2048; col0 = 1024 + (tx - 16) * 128; }

  #pragma unroll
  for (int mi = 0; mi < 4; mi++){
    #pragma unroll
    for (int r2 = 0; r2 < 4; r2++){
      const int gm = m0 + wr*64 + mi*16 + lg*4 + r2;
      if (gm < BROWS){
        const float rsv = isQ ? rs[gm] : 0.f;
        const float muv = isQ ? mu[gm] : 0.f;
        #pragma unroll
        for (int ni = 0; ni < 4; ni++){
          const int nl = wc*64 + ni*16 + l15;
          float v = acc[mi][ni][r2];
          if (isQ) v = 0.125f * (rsv * (v - muv * cg[tx*128 + nl]) + cb[tx*128 + nl]);
          outp[(size_t)gm * ostride + col0 + nl] = f2bf(v);
        }
      }
    }
  }
}

// ---------------------------------------------------------------- FC GEMM (r12/r7-proven)
// out = ctx @ Wfc + bias + resid. BM=64, BN=128, 3-buffer counted vmcnt(3).
__global__ __launch_bounds__(256) void fc_gemm(const ushort_t* __restrict__ A,
    const ushort_t* __restrict__ Bt, const float* __restrict__ bias,
    const float* __restrict__ resid, float* __restrict__ out){
  __shared__ __align__(16) ushort_t Asf[3][64 * 32];   // 12 KB
  __shared__ __align__(16) ushort_t Bsf[3][128 * 32];  // 24 KB
  const int tid = threadIdx.x;
  const int w = tid >> 6, lane = tid & 63;
  const int l15 = lane & 15, lg = lane >> 4;
  const int wr = w >> 1, wc = w & 1;

  const int bswz = ((int)blockIdx.x & 7) * 85 + ((int)blockIdx.x >> 3);   // 680 = 8*85
  const int ty = bswz >> 3, tx = bswz & 7;
  const int m0 = ty * 64, n0 = tx * 128;

  const int rch = lane >> 2, slot = lane & 3;
  const int gch = slot ^ ((rch >> 1) & 3);
  const ushort_t* a_src  = A  + (size_t)(m0 + w * 16 + rch) * DM + gch * 8;
  const ushort_t* b_src0 = Bt + (size_t)(n0 + w * 32      + rch) * DM + gch * 8;
  const ushort_t* b_src1 = Bt + (size_t)(n0 + w * 32 + 16 + rch) * DM + gch * 8;

  #define FSTAGE(P, T) do { \
    gload16(a_src  + (T) * 32, &Asf[P][(w * 16     ) * 32]); \
    gload16(b_src0 + (T) * 32, &Bsf[P][(w * 32     ) * 32]); \
    gload16(b_src1 + (T) * 32, &Bsf[P][(w * 32 + 16) * 32]); \
  } while(0)

  const int fs = lg ^ ((l15 >> 1) & 3);

  f32x4 acc[2][4];
  #pragma unroll
  for (int a = 0; a < 2; a++)
    #pragma unroll
    for (int b = 0; b < 4; b++) acc[a][b] = (f32x4){0.f,0.f,0.f,0.f};

  FSTAGE(0, 0);
  FSTAGE(1, 1);
  FENCE_VM3;
  BAR;

  int p = 0, p2 = 2;
  for (int kt = 0; kt < 32; ++kt){
    if (kt <= 29) FSTAGE(p2, kt + 2);

    s16x8 af[2], bf[4];
    #pragma unroll
    for (int mi = 0; mi < 2; mi++)
      af[mi] = *reinterpret_cast<const s16x8*>(&Asf[p][(wr*32 + mi*16 + l15) * 32 + fs * 8]);
    #pragma unroll
    for (int ni = 0; ni < 4; ni++)
      bf[ni] = *reinterpret_cast<const s16x8*>(&Bsf[p][(wc*64 + ni*16 + l15) * 32 + fs * 8]);
    #pragma unroll
    for (int mi = 0; mi < 2; mi++)
      #pragma unroll
      for (int ni = 0; ni < 4; ni++)
        acc[mi][ni] = __builtin_amdgcn_mfma_f32_16x16x32_bf16(af[mi], bf[ni], acc[mi][ni], 0, 0, 0);

    if (kt < 31){
      if (kt <= 29) FENCE_VM3;
      else          FENCE_VM0;
      BAR;
    }
    p  = (p  == 2) ? 0 : p  + 1;
    p2 = (p2 == 2) ? 0 : p2 + 1;
  }
  #undef FSTAGE

  #pragma unroll
  for (int mi = 0; mi < 2; mi++)
    #pragma unroll
    for (int ni = 0; ni < 4; ni++){
      const int gn = n0 + wc*64 + ni*16 + l15;
      #pragma unroll
      for (int r2 = 0; r2 < 4; r2++){
        const int gm = m0 + wr*32 + mi*16 + lg*4 + r2;
        out[(size_t)gm * DM + gn] = acc[mi][ni][r2] + bias[gn] + resid[(size_t)gm * DM + gn];
      }
    }
}

// ---------------------------------------------------------------- sparse PAM attention
__global__ __launch_bounds__(256) void attn_kernel(const ushort_t* __restrict__ Q,
    const ushort_t* __restrict__ KV, ushort_t* __restrict__ ctx){
  const int wid = threadIdx.x >> 6, lane = threadIdx.x & 63;
  const int gw = blockIdx.x * 4 + wid;
  const int b = gw / L_TOT;
  const int rem = gw - b * L_TOT;
  const int h = rem / 85;
  const int qt = rem - h * 85;
  const int l15 = lane & 15, g = lane >> 4;
  const int i = qt * 16 + l15;
  const int row = b * L_TOT + i;
  const int brow0 = b * L_TOT;

  int st, sz;
  if      (i < 1024){ st = 0;    sz = 1024; }
  else if (i < 1280){ st = 1024; sz = 256;  }
  else if (i < 1344){ st = 1280; sz = 64;   }
  else              { st = 1344; sz = 16;   }

  int key[10]; bool val[10];
  #pragma unroll
  for (int s = 0; s < 5; s++){
    int j = i - 2 + s;
    val[s] = (j >= st) && (j < st + sz);
    key[s] = val[s] ? j : i;
  }
  const bool haskid = (i >= 1024);
  const int cs = haskid ? (st - sz * 4 + (i - st) * 4) : i;
  #pragma unroll
  for (int c = 0; c < 4; c++){ key[5 + c] = haskid ? (cs + c) : i; val[5 + c] = haskid; }
  const bool haspar = (i < 1344);
  key[9] = haspar ? (st + sz + ((i - st) >> 2)) : i;
  val[9] = haspar;

  const int dcol = h * 64 + g * 16;
  const ushort_t* qp = Q + (size_t)row * DM + dcol;
  s16x8 q0 = *reinterpret_cast<const s16x8*>(qp);
  s16x8 q1 = *reinterpret_cast<const s16x8*>(qp + 8);
  float qf[16];
  #pragma unroll
  for (int j = 0; j < 8; j++){ qf[j] = b2f((ushort_t)q0[j]); qf[8 + j] = b2f((ushort_t)q1[j]); }

  size_t koff[10];
  float sc[10];
  #pragma unroll
  for (int s = 0; s < 10; s++){
    koff[s] = (size_t)(brow0 + key[s]) * 2048 + dcol;
    const ushort_t* kp = KV + koff[s];
    s16x8 k0 = *reinterpret_cast<const s16x8*>(kp);
    s16x8 k1 = *reinterpret_cast<const s16x8*>(kp + 8);
    float p = 0.f;
    #pragma unroll
    for (int j = 0; j < 8; j++){
      p += qf[j]     * b2f((ushort_t)k0[j]);
      p += qf[8 + j] * b2f((ushort_t)k1[j]);
    }
    p += __shfl_xor(p, 16);
    p += __shfl_xor(p, 32);
    sc[s] = val[s] ? p : -1e30f;
  }

  float m = sc[0];
  #pragma unroll
  for (int s = 1; s < 10; s++) m = fmaxf(m, sc[s]);
  float e[10]; float sum = 0.f;
  #pragma unroll
  for (int s = 0; s < 10; s++){ e[s] = __expf(sc[s] - m); sum += e[s]; }
  const float inv = 1.0f / sum;

  float accv[16];
  #pragma unroll
  for (int j = 0; j < 16; j++) accv[j] = 0.f;
  #pragma unroll
  for (int s = 0; s < 10; s++){
    const ushort_t* vp = KV + koff[s] + 1024;
    s16x8 v0 = *reinterpret_cast<const s16x8*>(vp);
    s16x8 v1 = *reinterpret_cast<const s16x8*>(vp + 8);
    const float w = e[s];
    #pragma unroll
    for (int j = 0; j < 8; j++){
      accv[j]     += w * b2f((ushort_t)v0[j]);
      accv[8 + j] += w * b2f((ushort_t)v1[j]);
    }
  }

  // sigma store (feeds fc_gemm staging)
  ushort_t* op = ctx + (size_t)row * DM + 32 * (2 * h + (g >> 1)) + 4 * (g & 1);
  #pragma unroll
  for (int m2 = 0; m2 < 4; m2++){
    uint2 o;
    o.x = cvtpk(accv[4*m2+0]*inv, accv[4*m2+1]*inv);
    o.y = cvtpk(accv[4*m2+2]*inv, accv[4*m2+3]*inv);
    *reinterpret_cast<uint2*>(op + 8 * m2) = o;
  }
}

// ---------------------------------------------------------------- launch
extern "C" void kernel_launch(void* const* d_in, const int* in_sizes, int n_in,
                              void* d_out, int out_size, void* d_ws, size_t ws_size,
                              hipStream_t stream){
  (void)in_sizes; (void)n_in; (void)out_size; (void)ws_size;
  const float* x     = (const float*)d_in[0];
  const float* Wq    = (const float*)d_in[1];
  const float* Wk    = (const float*)d_in[2];
  const float* Wv    = (const float*)d_in[3];
  const float* Wfc   = (const float*)d_in[4];
  const float* bfc   = (const float*)d_in[5];
  const float* gamma = (const float*)d_in[6];
  const float* beta  = (const float*)d_in[7];
  float* out = (float*)d_out;

  char* ws = (char*)d_ws;
  const size_t SLAB = (size_t)BROWS * DM * sizeof(ushort_t);   // 11,141,120 B
  ushort_t* Wqkv_t = (ushort_t*)(ws);                           // 6 MB (sigma)
  ushort_t* Wfc_t  = (ushort_t*)(ws + 6291456);                 // 2 MB (sigma)
  float*    cg     = (float*)(ws + 8388608);
  float*    cb     = (float*)(ws + 8392704);
  float*    muv    = (float*)(ws + 8396800);
  float*    rsv    = (float*)(ws + 8418560);
  ushort_t* Qb  = (ushort_t*)(ws + SLAB);       // Q -> ctx (in place, ctx sigma)
  ushort_t* ctx = Qb;
  ushort_t* KVb = (ushort_t*)(ws + 2 * SLAB);   // [row][K|V] stride 2048
  ushort_t* x_bf = (ushort_t*)(ws + 4 * SLAB);  // x bf16, sigma

  prep_kernel<<<BROWS + 64 + 1024, 256, 0, stream>>>(x, Wq, Wk, Wv, Wfc, gamma, beta,
      muv, rsv, x_bf, cg, cb, Wqkv_t, Wfc_t);
  qkv_gemm<<<1032, 256, 0, stream>>>(x_bf, Wqkv_t, Qb, KVb, cg, cb, muv, rsv);
  attn_kernel<<<L_TOT, 256, 0, stream>>>(Qb, KVb, ctx);
  fc_gemm<<<680, 256, 0, stream>>>(ctx, Wfc_t, bfc, x, out);
}

// Round 16
// 134.424 us; speedup vs baseline: 1.1646x; 1.1646x over previous
//
#include <hip/hip_runtime.h>

typedef float f32x4 __attribute__((ext_vector_type(4)));
typedef short s16x8 __attribute__((ext_vector_type(8)));
typedef unsigned short ushort_t;

#define L_TOT 1360
#define BROWS 5440   // 4 * 1360
#define DM    1024

__device__ __forceinline__ float b2f(ushort_t u){
  union { unsigned int u; float f; } v; v.u = ((unsigned int)u) << 16; return v.f;
}
__device__ __forceinline__ ushort_t f2bf(float f){
  union { float f; unsigned int u; } v; v.f = f;
  unsigned int u = v.u;
  unsigned int r = u + 0x7fffu + ((u >> 16) & 1u);
  return (ushort_t)(r >> 16);
}
__device__ __forceinline__ unsigned cvtpk(float lo, float hi){
  unsigned r; asm("v_cvt_pk_bf16_f32 %0, %1, %2" : "=v"(r) : "v"(lo), "v"(hi)); return r;
}
__device__ __forceinline__ void gload16(const ushort_t* g, ushort_t* l){
  __builtin_amdgcn_global_load_lds(
      (const __attribute__((address_space(1))) unsigned int*)g,
      (__attribute__((address_space(3))) unsigned int*)l, 16, 0, 0);
}

#define FENCE_VM3  asm volatile("s_waitcnt vmcnt(3)" ::: "memory")
#define FENCE_VM0  asm volatile("s_waitcnt vmcnt(0)" ::: "memory")
#define BAR        __builtin_amdgcn_s_barrier()

// ---------------------------------------------------------------------------
// sigma k-layout: within each 32-k block, quads stored [q0 q4 q1 q5 q2 q6 q3 q7]
// (16B chunk c = MFMA fragment k-set {4c+i} u {16+4c+i}); LDS slot-XOR involution
// slot s of row r holds chunk s ^ ((r>>1)&3). Verified r4: 0 bank conflicts.
// This is the measured-best configuration (r12, 134.4 us total).
// ---------------------------------------------------------------------------

// ---------------------------------------------------------------- fused prep
__global__ __launch_bounds__(256) void prep_kernel(const float* __restrict__ x,
    const float* __restrict__ Wq, const float* __restrict__ Wk,
    const float* __restrict__ Wv, const float* __restrict__ Wfc,
    const float* __restrict__ gamma, const float* __restrict__ beta,
    float* __restrict__ mu, float* __restrict__ rs, ushort_t* __restrict__ xbf,
    float* __restrict__ cg, float* __restrict__ cb,
    ushort_t* __restrict__ Wqkv_t, ushort_t* __restrict__ Wfc_t){
  __shared__ float smem[64 * 68];
  const int bid = blockIdx.x;
  const int t = threadIdx.x;

  if (bid < BROWS){
    const int row = bid;
    f32x4 v = *reinterpret_cast<const f32x4*>(x + (size_t)row * DM + t * 4);
    {
      const int off = 32 * (t >> 3) + 8 * (t & 3) + 4 * ((t >> 2) & 1);
      uint2 o; o.x = cvtpk(v.x, v.y); o.y = cvtpk(v.z, v.w);
      *reinterpret_cast<uint2*>(xbf + (size_t)row * DM + off) = o;
    }
    float s  = v.x + v.y + v.z + v.w;
    float s2 = v.x*v.x + v.y*v.y + v.z*v.z + v.w*v.w;
    #pragma unroll
    for (int off = 32; off; off >>= 1){ s += __shfl_xor(s, off); s2 += __shfl_xor(s2, off); }
    const int wid = t >> 6, lane = t & 63;
    if (lane == 0){ smem[wid] = s; smem[4 + wid] = s2; }
    __syncthreads();
    if (t == 0){
      s  = smem[0] + smem[1] + smem[2] + smem[3];
      s2 = smem[4] + smem[5] + smem[6] + smem[7];
      const float m = s * (1.0f / DM);
      const float var = s2 * (1.0f / DM) - m * m;
      mu[row] = m;
      rs[row] = rsqrtf(var + 1e-6f);
    }
  } else if (bid < BROWS + 64){
    float* shg = smem;
    float* shb = smem + 16 * 17;
    const int c = t & 15;
    const int kq = t >> 4;
    const int col = (bid - BROWS) * 16 + c;
    float sg = 0.f, sb = 0.f;
    for (int k = kq * 64; k < kq * 64 + 64; k++){
      const float w = Wq[(size_t)k * DM + col];
      sg += gamma[k] * w;
      sb += beta[k] * w;
    }
    shg[kq * 17 + c] = sg; shb[kq * 17 + c] = sb;
    __syncthreads();
    if (kq == 0){
      float tg = 0.f, tb = 0.f;
      #pragma unroll
      for (int q2 = 0; q2 < 16; q2++){ tg += shg[q2 * 17 + c]; tb += shb[q2 * 17 + c]; }
      cg[col] = tg; cb[col] = tb;
    }
  } else {
    const int q2 = bid - BROWS - 64;
    const int z = q2 >> 8, rem = q2 & 255;
    const int kx = rem & 15, ny = rem >> 4;
    const float* W = (z == 0) ? Wq : (z == 1) ? Wk : (z == 2) ? Wv : Wfc;
    ushort_t* D = (z == 3) ? Wfc_t : (Wqkv_t + (size_t)z * DM * DM);
    const int k0 = kx * 64, n0 = ny * 64;
    const int tr = t >> 4, tc = t & 15;
    #pragma unroll
    for (int it = 0; it < 4; it++){
      const int r = tr + it * 16;
      f32x4 v = *reinterpret_cast<const f32x4*>(W + (size_t)(k0 + r) * DM + n0 + tc * 4);
      if (z == 0){ const float g = gamma[k0 + r]; v.x *= g; v.y *= g; v.z *= g; v.w *= g; }
      *reinterpret_cast<f32x4*>(&smem[r * 68 + tc * 4]) = v;
    }
    __syncthreads();
    const int soff = k0 + 32 * (tc >> 3) + 8 * (tc & 3) + 4 * ((tc >> 2) & 1);
    #pragma unroll
    for (int it = 0; it < 4; it++){
      const int rn = tr + it * 16;
      float a = smem[(tc*4+0) * 68 + rn], b = smem[(tc*4+1) * 68 + rn];
      float c = smem[(tc*4+2) * 68 + rn], d = smem[(tc*4+3) * 68 + rn];
      uint2 w; w.x = cvtpk(a, b); w.y = cvtpk(c, d);
      *reinterpret_cast<uint2*>(D + (size_t)(n0 + rn) * DM + soff) = w;
    }
  }
}

// ---------------------------------------------------------------- fused QKV GEMM (r12-proven)
// 128x256 tile, BK=32, 8 waves (2m x 4n), wave-tile 64x64 (16 MFMA/iter).
// LDS: 3 bufs x 24KB = 72KB. 3-buf counted-vmcnt(3), 1 barrier/K-step.
// Grid 516 = 504 heavies (8 x 63, XCD-chunked) + 12 ragged tails last.
__global__ __launch_bounds__(512, 4) void qkv_gemm(const ushort_t* __restrict__ A,
    const ushort_t* __restrict__ Bt, ushort_t* __restrict__ Qb, ushort_t* __restrict__ KVb,
    const float* __restrict__ cg, const float* __restrict__ cb,
    const float* __restrict__ mu, const float* __restrict__ rs){
  __shared__ __align__(16) ushort_t As[3][128 * 32];   // 24 KB
  __shared__ __align__(16) ushort_t Bs[3][256 * 32];   // 48 KB
  const int tid = threadIdx.x;
  const int w = tid >> 6, lane = tid & 63;
  const int l15 = lane & 15, lg = lane >> 4;
  const int wr = w >> 2, wc = w & 3;

  int ty, tx;
  if (blockIdx.x < 504){
    const int idx = (int)blockIdx.x;                    // 504 = 8 * 63
    const int xcd = idx & 7, loc = idx >> 3;
    const int wg = xcd * 63 + loc;
    ty = wg / 12; tx = wg % 12;
  } else {
    ty = 42; tx = (int)blockIdx.x - 504;
  }
  const int m0 = ty * 128, n0 = tx * 256;

  const int rch = lane >> 2, slot = lane & 3;
  const int gch = slot ^ ((rch >> 1) & 3);
  int arow = m0 + w * 16 + rch; if (arow > BROWS - 1) arow = BROWS - 1;
  const ushort_t* a_src  = A  + (size_t)arow * DM + gch * 8;
  const ushort_t* b_src0 = Bt + (size_t)(n0 + w * 32      + rch) * DM + gch * 8;
  const ushort_t* b_src1 = Bt + (size_t)(n0 + w * 32 + 16 + rch) * DM + gch * 8;

  #define STAGE(P, T) do { \
    gload16(a_src  + (T) * 32, &As[P][(w * 16     ) * 32]); \
    gload16(b_src0 + (T) * 32, &Bs[P][(w * 32     ) * 32]); \
    gload16(b_src1 + (T) * 32, &Bs[P][(w * 32 + 16) * 32]); \
  } while(0)

  const int fs = lg ^ ((l15 >> 1) & 3);

  int miN = (BROWS - m0 - wr * 64 + 15) >> 4;
  if (miN > 4) miN = 4;
  if (miN < 0) miN = 0;

  f32x4 acc[4][4];
  #pragma unroll
  for (int a = 0; a < 4; a++)
    #pragma unroll
    for (int b = 0; b < 4; b++) acc[a][b] = (f32x4){0.f,0.f,0.f,0.f};

  STAGE(0, 0);
  STAGE(1, 1);
  FENCE_VM3;
  BAR;

  int p = 0, p2 = 2;
  for (int kt = 0; kt < 32; ++kt){
    if (kt <= 29) STAGE(p2, kt + 2);

    s16x8 af[4], bf[4];
    #pragma unroll
    for (int ni = 0; ni < 4; ni++)
      bf[ni] = *reinterpret_cast<const s16x8*>(&Bs[p][(wc*64 + ni*16 + l15) * 32 + fs * 8]);
    #pragma unroll
    for (int mi = 0; mi < 4; mi++)
      if (mi < miN)
        af[mi] = *reinterpret_cast<const s16x8*>(&As[p][(wr*64 + mi*16 + l15) * 32 + fs * 8]);

    __builtin_amdgcn_s_setprio(1);
    #pragma unroll
    for (int mi = 0; mi < 4; mi++)
      if (mi < miN)
        #pragma unroll
        for (int ni = 0; ni < 4; ni++)
          acc[mi][ni] = __builtin_amdgcn_mfma_f32_16x16x32_bf16(af[mi], bf[ni], acc[mi][ni], 0, 0, 0);
    __builtin_amdgcn_s_setprio(0);

    if (kt < 31){
      if (kt <= 29) FENCE_VM3;
      else          FENCE_VM0;
      BAR;
    }
    p  = (p  == 2) ? 0 : p  + 1;
    p2 = (p2 == 2) ? 0 : p2 + 1;
  }
  #undef STAGE

  const bool isQ = (tx < 4);
  ushort_t* outp; int ostride, col0;
  if (tx < 4)      { outp = Qb;  ostride = 1024; col0 = tx * 256; }
  else if (tx < 8) { outp = KVb; ostride = 2048; col0 = (tx - 4) * 256; }
  else             { outp = KVb; ostride = 2048; col0 = 1024 + (tx - 8) * 256; }

  #pragma unroll
  for (int mi = 0; mi < 4; mi++){
    #pragma unroll
    for (int r2 = 0; r2 < 4; r2++){
      const int gm = m0 + wr*64 + mi*16 + lg*4 + r2;
      if (gm < BROWS){
        const float rsv = isQ ? rs[gm] : 0.f;
        const float muv = isQ ? mu[gm] : 0.f;
        #pragma unroll
        for (int ni = 0; ni < 4; ni++){
          const int nl = wc*64 + ni*16 + l15;
          float v = acc[mi][ni][r2];
          if (isQ) v = 0.125f * (rsv * (v - muv * cg[tx*256 + nl]) + cb[tx*256 + nl]);
          outp[(size_t)gm * ostride + col0 + nl] = f2bf(v);
        }
      }
    }
  }
}

// ---------------------------------------------------------------- FC GEMM (r7-proven)
// out = ctx @ Wfc + bias + resid. BM=64, BN=128, 3-buffer counted vmcnt(3).
__global__ __launch_bounds__(256) void fc_gemm(const ushort_t* __restrict__ A,
    const ushort_t* __restrict__ Bt, const float* __restrict__ bias,
    const float* __restrict__ resid, float* __restrict__ out){
  __shared__ __align__(16) ushort_t Asf[3][64 * 32];   // 12 KB
  __shared__ __align__(16) ushort_t Bsf[3][128 * 32];  // 24 KB
  const int tid = threadIdx.x;
  const int w = tid >> 6, lane = tid & 63;
  const int l15 = lane & 15, lg = lane >> 4;
  const int wr = w >> 1, wc = w & 1;

  const int bswz = ((int)blockIdx.x & 7) * 85 + ((int)blockIdx.x >> 3);   // 680 = 8*85
  const int ty = bswz >> 3, tx = bswz & 7;
  const int m0 = ty * 64, n0 = tx * 128;

  const int rch = lane >> 2, slot = lane & 3;
  const int gch = slot ^ ((rch >> 1) & 3);
  const ushort_t* a_src  = A  + (size_t)(m0 + w * 16 + rch) * DM + gch * 8;
  const ushort_t* b_src0 = Bt + (size_t)(n0 + w * 32      + rch) * DM + gch * 8;
  const ushort_t* b_src1 = Bt + (size_t)(n0 + w * 32 + 16 + rch) * DM + gch * 8;

  #define FSTAGE(P, T) do { \
    gload16(a_src  + (T) * 32, &Asf[P][(w * 16     ) * 32]); \
    gload16(b_src0 + (T) * 32, &Bsf[P][(w * 32     ) * 32]); \
    gload16(b_src1 + (T) * 32, &Bsf[P][(w * 32 + 16) * 32]); \
  } while(0)

  const int fs = lg ^ ((l15 >> 1) & 3);

  f32x4 acc[2][4];
  #pragma unroll
  for (int a = 0; a < 2; a++)
    #pragma unroll
    for (int b = 0; b < 4; b++) acc[a][b] = (f32x4){0.f,0.f,0.f,0.f};

  FSTAGE(0, 0);
  FSTAGE(1, 1);
  FENCE_VM3;
  BAR;

  int p = 0, p2 = 2;
  for (int kt = 0; kt < 32; ++kt){
    if (kt <= 29) FSTAGE(p2, kt + 2);

    s16x8 af[2], bf[4];
    #pragma unroll
    for (int mi = 0; mi < 2; mi++)
      af[mi] = *reinterpret_cast<const s16x8*>(&Asf[p][(wr*32 + mi*16 + l15) * 32 + fs * 8]);
    #pragma unroll
    for (int ni = 0; ni < 4; ni++)
      bf[ni] = *reinterpret_cast<const s16x8*>(&Bsf[p][(wc*64 + ni*16 + l15) * 32 + fs * 8]);
    #pragma unroll
    for (int mi = 0; mi < 2; mi++)
      #pragma unroll
      for (int ni = 0; ni < 4; ni++)
        acc[mi][ni] = __builtin_amdgcn_mfma_f32_16x16x32_bf16(af[mi], bf[ni], acc[mi][ni], 0, 0, 0);

    if (kt < 31){
      if (kt <= 29) FENCE_VM3;
      else          FENCE_VM0;
      BAR;
    }
    p  = (p  == 2) ? 0 : p  + 1;
    p2 = (p2 == 2) ? 0 : p2 + 1;
  }
  #undef FSTAGE

  #pragma unroll
  for (int mi = 0; mi < 2; mi++)
    #pragma unroll
    for (int ni = 0; ni < 4; ni++){
      const int gn = n0 + wc*64 + ni*16 + l15;
      #pragma unroll
      for (int r2 = 0; r2 < 4; r2++){
        const int gm = m0 + wr*32 + mi*16 + lg*4 + r2;
        out[(size_t)gm * DM + gn] = acc[mi][ni][r2] + bias[gn] + resid[(size_t)gm * DM + gn];
      }
    }
}

// ---------------------------------------------------------------- sparse PAM attention
__global__ __launch_bounds__(256) void attn_kernel(const ushort_t* __restrict__ Q,
    const ushort_t* __restrict__ KV, ushort_t* __restrict__ ctx){
  const int wid = threadIdx.x >> 6, lane = threadIdx.x & 63;
  const int gw = blockIdx.x * 4 + wid;
  const int b = gw / L_TOT;
  const int rem = gw - b * L_TOT;
  const int h = rem / 85;
  const int qt = rem - h * 85;
  const int l15 = lane & 15, g = lane >> 4;
  const int i = qt * 16 + l15;
  const int row = b * L_TOT + i;
  const int brow0 = b * L_TOT;

  int st, sz;
  if      (i < 1024){ st = 0;    sz = 1024; }
  else if (i < 1280){ st = 1024; sz = 256;  }
  else if (i < 1344){ st = 1280; sz = 64;   }
  else              { st = 1344; sz = 16;   }

  int key[10]; bool val[10];
  #pragma unroll
  for (int s = 0; s < 5; s++){
    int j = i - 2 + s;
    val[s] = (j >= st) && (j < st + sz);
    key[s] = val[s] ? j : i;
  }
  const bool haskid = (i >= 1024);
  const int cs = haskid ? (st - sz * 4 + (i - st) * 4) : i;
  #pragma unroll
  for (int c = 0; c < 4; c++){ key[5 + c] = haskid ? (cs + c) : i; val[5 + c] = haskid; }
  const bool haspar = (i < 1344);
  key[9] = haspar ? (st + sz + ((i - st) >> 2)) : i;
  val[9] = haspar;

  const int dcol = h * 64 + g * 16;
  const ushort_t* qp = Q + (size_t)row * DM + dcol;
  s16x8 q0 = *reinterpret_cast<const s16x8*>(qp);
  s16x8 q1 = *reinterpret_cast<const s16x8*>(qp + 8);
  float qf[16];
  #pragma unroll
  for (int j = 0; j < 8; j++){ qf[j] = b2f((ushort_t)q0[j]); qf[8 + j] = b2f((ushort_t)q1[j]); }

  size_t koff[10];
  float sc[10];
  #pragma unroll
  for (int s = 0; s < 10; s++){
    koff[s] = (size_t)(brow0 + key[s]) * 2048 + dcol;
    const ushort_t* kp = KV + koff[s];
    s16x8 k0 = *reinterpret_cast<const s16x8*>(kp);
    s16x8 k1 = *reinterpret_cast<const s16x8*>(kp + 8);
    float p = 0.f;
    #pragma unroll
    for (int j = 0; j < 8; j++){
      p += qf[j]     * b2f((ushort_t)k0[j]);
      p += qf[8 + j] * b2f((ushort_t)k1[j]);
    }
    p += __shfl_xor(p, 16);
    p += __shfl_xor(p, 32);
    sc[s] = val[s] ? p : -1e30f;
  }

  float m = sc[0];
  #pragma unroll
  for (int s = 1; s < 10; s++) m = fmaxf(m, sc[s]);
  float e[10]; float sum = 0.f;
  #pragma unroll
  for (int s = 0; s < 10; s++){ e[s] = __expf(sc[s] - m); sum += e[s]; }
  const float inv = 1.0f / sum;

  float accv[16];
  #pragma unroll
  for (int j = 0; j < 16; j++) accv[j] = 0.f;
  #pragma unroll
  for (int s = 0; s < 10; s++){
    const ushort_t* vp = KV + koff[s] + 1024;
    s16x8 v0 = *reinterpret_cast<const s16x8*>(vp);
    s16x8 v1 = *reinterpret_cast<const s16x8*>(vp + 8);
    const float w = e[s];
    #pragma unroll
    for (int j = 0; j < 8; j++){
      accv[j]     += w * b2f((ushort_t)v0[j]);
      accv[8 + j] += w * b2f((ushort_t)v1[j]);
    }
  }

  // sigma store (feeds fc_gemm staging)
  ushort_t* op = ctx + (size_t)row * DM + 32 * (2 * h + (g >> 1)) + 4 * (g & 1);
  #pragma unroll
  for (int m2 = 0; m2 < 4; m2++){
    uint2 o;
    o.x = cvtpk(accv[4*m2+0]*inv, accv[4*m2+1]*inv);
    o.y = cvtpk(accv[4*m2+2]*inv, accv[4*m2+3]*inv);
    *reinterpret_cast<uint2*>(op + 8 * m2) = o;
  }
}

// ---------------------------------------------------------------- launch
extern "C" void kernel_launch(void* const* d_in, const int* in_sizes, int n_in,
                              void* d_out, int out_size, void* d_ws, size_t ws_size,
                              hipStream_t stream){
  (void)in_sizes; (void)n_in; (void)out_size; (void)ws_size;
  const float* x     = (const float*)d_in[0];
  const float* Wq    = (const float*)d_in[1];
  const float* Wk    = (const float*)d_in[2];
  const float* Wv    = (const float*)d_in[3];
  const float* Wfc   = (const float*)d_in[4];
  const float* bfc   = (const float*)d_in[5];
  const float* gamma = (const float*)d_in[6];
  const float* beta  = (const float*)d_in[7];
  float* out = (float*)d_out;

  char* ws = (char*)d_ws;
  const size_t SLAB = (size_t)BROWS * DM * sizeof(ushort_t);   // 11,141,120 B
  ushort_t* Wqkv_t = (ushort_t*)(ws);                           // 6 MB (sigma)
  ushort_t* Wfc_t  = (ushort_t*)(ws + 6291456);                 // 2 MB (sigma)
  float*    cg     = (float*)(ws + 8388608);
  float*    cb     = (float*)(ws + 8392704);
  float*    muv    = (float*)(ws + 8396800);
  float*    rsv    = (float*)(ws + 8418560);
  ushort_t* Qb  = (ushort_t*)(ws + SLAB);       // Q -> ctx (in place, ctx sigma)
  ushort_t* ctx = Qb;
  ushort_t* KVb = (ushort_t*)(ws + 2 * SLAB);   // [row][K|V] stride 2048
  ushort_t* x_bf = (ushort_t*)(ws + 4 * SLAB);  // x bf16, sigma

  prep_kernel<<<BROWS + 64 + 1024, 256, 0, stream>>>(x, Wq, Wk, Wv, Wfc, gamma, beta,
      muv, rsv, x_bf, cg, cb, Wqkv_t, Wfc_t);
  qkv_gemm<<<516, 512, 0, stream>>>(x_bf, Wqkv_t, Qb, KVb, cg, cb, muv, rsv);
  attn_kernel<<<L_TOT, 256, 0, stream>>>(Qb, KVb, ctx);
  fc_gemm<<<680, 256, 0, stream>>>(ctx, Wfc_t, bfc, x, out);
}

// Round 17
// 134.129 us; speedup vs baseline: 1.1671x; 1.0022x over previous
//
#include <hip/hip_runtime.h>

typedef float f32x4 __attribute__((ext_vector_type(4)));
typedef short s16x8 __attribute__((ext_vector_type(8)));
typedef unsigned short ushort_t;

#define L_TOT 1360
#define BROWS 5440   // 4 * 1360
#define DM    1024

__device__ __forceinline__ float b2f(ushort_t u){
  union { unsigned int u; float f; } v; v.u = ((unsigned int)u) << 16; return v.f;
}
__device__ __forceinline__ ushort_t f2bf(float f){
  union { float f; unsigned int u; } v; v.f = f;
  unsigned int u = v.u;
  unsigned int r = u + 0x7fffu + ((u >> 16) & 1u);
  return (ushort_t)(r >> 16);
}
__device__ __forceinline__ unsigned cvtpk(float lo, float hi){
  unsigned r; asm("v_cvt_pk_bf16_f32 %0, %1, %2" : "=v"(r) : "v"(lo), "v"(hi)); return r;
}
__device__ __forceinline__ void gload16(const ushort_t* g, ushort_t* l){
  __builtin_amdgcn_global_load_lds(
      (const __attribute__((address_space(1))) unsigned int*)g,
      (__attribute__((address_space(3))) unsigned int*)l, 16, 0, 0);
}

#define FENCE_VM3  asm volatile("s_waitcnt vmcnt(3)" ::: "memory")
#define FENCE_VM0  asm volatile("s_waitcnt vmcnt(0)" ::: "memory")
#define BAR        __builtin_amdgcn_s_barrier()

// ---------------------------------------------------------------------------
// sigma k-layout: within each 32-k block, quads stored [q0 q4 q1 q5 q2 q6 q3 q7]
// (16B chunk c = MFMA fragment k-set {4c+i} u {16+4c+i}); LDS slot-XOR involution
// slot s of row r holds chunk s ^ ((r>>1)&3). Verified r4: 0 bank conflicts.
// Base: r12 measured-best (134.4 us). This round: prep-only A/B (r13's prep,
// fc/qkv/attn byte-identical) to deconfound r13's bundled regression.
// ---------------------------------------------------------------------------

// ---------------------------------------------------------------- fused prep (r13 version)
// blocks [0,1360): stats+x->bf16, wave-per-row (4 rows/block, no smem);
// [1360,1424): cvec; [1424,2448): weight transposes.
__global__ __launch_bounds__(256) void prep_kernel(const float* __restrict__ x,
    const float* __restrict__ Wq, const float* __restrict__ Wk,
    const float* __restrict__ Wv, const float* __restrict__ Wfc,
    const float* __restrict__ gamma, const float* __restrict__ beta,
    float* __restrict__ mu, float* __restrict__ rs, ushort_t* __restrict__ xbf,
    float* __restrict__ cg, float* __restrict__ cb,
    ushort_t* __restrict__ Wqkv_t, ushort_t* __restrict__ Wfc_t){
  __shared__ float smem[64 * 68];
  const int bid = blockIdx.x;
  const int t = threadIdx.x;

  if (bid < 1360){
    // ---- stats + x->bf16(sigma): wave w owns row bid*4+w; lane owns 16 cols.
    const int row = bid * 4 + (t >> 6);
    const int lane = t & 63;
    const float* xr = x + (size_t)row * DM + lane * 16;
    f32x4 v0 = *reinterpret_cast<const f32x4*>(xr);
    f32x4 v1 = *reinterpret_cast<const f32x4*>(xr + 4);
    f32x4 v2 = *reinterpret_cast<const f32x4*>(xr + 8);
    f32x4 v3 = *reinterpret_cast<const f32x4*>(xr + 12);
    // sigma write: lane covers quads J=4l..4l+3 -> offset 32*(l>>1)+8*j+4*(l&1)
    ushort_t* op = xbf + (size_t)row * DM + 32 * (lane >> 1) + 4 * (lane & 1);
    uint2 o;
    o.x = cvtpk(v0.x, v0.y); o.y = cvtpk(v0.z, v0.w); *reinterpret_cast<uint2*>(op)      = o;
    o.x = cvtpk(v1.x, v1.y); o.y = cvtpk(v1.z, v1.w); *reinterpret_cast<uint2*>(op + 8)  = o;
    o.x = cvtpk(v2.x, v2.y); o.y = cvtpk(v2.z, v2.w); *reinterpret_cast<uint2*>(op + 16) = o;
    o.x = cvtpk(v3.x, v3.y); o.y = cvtpk(v3.z, v3.w); *reinterpret_cast<uint2*>(op + 24) = o;
    float s = 0.f, s2 = 0.f;
    #pragma unroll
    for (int j = 0; j < 4; j++){
      f32x4 v = (j == 0) ? v0 : (j == 1) ? v1 : (j == 2) ? v2 : v3;
      s  += v.x + v.y + v.z + v.w;
      s2 += v.x*v.x + v.y*v.y + v.z*v.z + v.w*v.w;
    }
    #pragma unroll
    for (int off = 32; off; off >>= 1){ s += __shfl_xor(s, off); s2 += __shfl_xor(s2, off); }
    if (lane == 0){
      const float m = s * (1.0f / DM);
      const float var = s2 * (1.0f / DM) - m * m;
      mu[row] = m;
      rs[row] = rsqrtf(var + 1e-6f);
    }
  } else if (bid < 1424){
    // ---- cvec: cg = gamma^T Wq, cb = beta^T Wq
    float* shg = smem;
    float* shb = smem + 16 * 17;
    const int c = t & 15;
    const int kq = t >> 4;
    const int col = (bid - 1360) * 16 + c;
    float sg = 0.f, sb = 0.f;
    for (int k = kq * 64; k < kq * 64 + 64; k++){
      const float w = Wq[(size_t)k * DM + col];
      sg += gamma[k] * w;
      sb += beta[k] * w;
    }
    shg[kq * 17 + c] = sg; shb[kq * 17 + c] = sb;
    __syncthreads();
    if (kq == 0){
      float tg = 0.f, tb = 0.f;
      #pragma unroll
      for (int q2 = 0; q2 < 16; q2++){ tg += shg[q2 * 17 + c]; tb += shb[q2 * 17 + c]; }
      cg[col] = tg; cb[col] = tb;
    }
  } else {
    // ---- weight transpose -> sigma bf16 B^T
    const int q2 = bid - 1424;
    const int z = q2 >> 8, rem = q2 & 255;
    const int kx = rem & 15, ny = rem >> 4;
    const float* W = (z == 0) ? Wq : (z == 1) ? Wk : (z == 2) ? Wv : Wfc;
    ushort_t* D = (z == 3) ? Wfc_t : (Wqkv_t + (size_t)z * DM * DM);
    const int k0 = kx * 64, n0 = ny * 64;
    const int tr = t >> 4, tc = t & 15;
    #pragma unroll
    for (int it = 0; it < 4; it++){
      const int r = tr + it * 16;
      f32x4 v = *reinterpret_cast<const f32x4*>(W + (size_t)(k0 + r) * DM + n0 + tc * 4);
      if (z == 0){ const float g = gamma[k0 + r]; v.x *= g; v.y *= g; v.z *= g; v.w *= g; }
      *reinterpret_cast<f32x4*>(&smem[r * 68 + tc * 4]) = v;
    }
    __syncthreads();
    const int soff = k0 + 32 * (tc >> 3) + 8 * (tc & 3) + 4 * ((tc >> 2) & 1);
    #pragma unroll
    for (int it = 0; it < 4; it++){
      const int rn = tr + it * 16;
      float a = smem[(tc*4+0) * 68 + rn], b = smem[(tc*4+1) * 68 + rn];
      float c = smem[(tc*4+2) * 68 + rn], d = smem[(tc*4+3) * 68 + rn];
      uint2 w; w.x = cvtpk(a, b); w.y = cvtpk(c, d);
      *reinterpret_cast<uint2*>(D + (size_t)(n0 + rn) * DM + soff) = w;
    }
  }
}

// ---------------------------------------------------------------- fused QKV GEMM (r12-proven)
// 128x256 tile, BK=32, 8 waves (2m x 4n), wave-tile 64x64 (16 MFMA/iter).
// LDS: 3 bufs x 24KB = 72KB. 3-buf counted-vmcnt(3), 1 barrier/K-step.
// Grid 516 = 504 heavies (8 x 63, XCD-chunked) + 12 ragged tails last.
__global__ __launch_bounds__(512, 4) void qkv_gemm(const ushort_t* __restrict__ A,
    const ushort_t* __restrict__ Bt, ushort_t* __restrict__ Qb, ushort_t* __restrict__ KVb,
    const float* __restrict__ cg, const float* __restrict__ cb,
    const float* __restrict__ mu, const float* __restrict__ rs){
  __shared__ __align__(16) ushort_t As[3][128 * 32];   // 24 KB
  __shared__ __align__(16) ushort_t Bs[3][256 * 32];   // 48 KB
  const int tid = threadIdx.x;
  const int w = tid >> 6, lane = tid & 63;
  const int l15 = lane & 15, lg = lane >> 4;
  const int wr = w >> 2, wc = w & 3;

  int ty, tx;
  if (blockIdx.x < 504){
    const int idx = (int)blockIdx.x;                    // 504 = 8 * 63
    const int xcd = idx & 7, loc = idx >> 3;
    const int wg = xcd * 63 + loc;
    ty = wg / 12; tx = wg % 12;
  } else {
    ty = 42; tx = (int)blockIdx.x - 504;
  }
  const int m0 = ty * 128, n0 = tx * 256;

  const int rch = lane >> 2, slot = lane & 3;
  const int gch = slot ^ ((rch >> 1) & 3);
  int arow = m0 + w * 16 + rch; if (arow > BROWS - 1) arow = BROWS - 1;
  const ushort_t* a_src  = A  + (size_t)arow * DM + gch * 8;
  const ushort_t* b_src0 = Bt + (size_t)(n0 + w * 32      + rch) * DM + gch * 8;
  const ushort_t* b_src1 = Bt + (size_t)(n0 + w * 32 + 16 + rch) * DM + gch * 8;

  #define STAGE(P, T) do { \
    gload16(a_src  + (T) * 32, &As[P][(w * 16     ) * 32]); \
    gload16(b_src0 + (T) * 32, &Bs[P][(w * 32     ) * 32]); \
    gload16(b_src1 + (T) * 32, &Bs[P][(w * 32 + 16) * 32]); \
  } while(0)

  const int fs = lg ^ ((l15 >> 1) & 3);

  int miN = (BROWS - m0 - wr * 64 + 15) >> 4;
  if (miN > 4) miN = 4;
  if (miN < 0) miN = 0;

  f32x4 acc[4][4];
  #pragma unroll
  for (int a = 0; a < 4; a++)
    #pragma unroll
    for (int b = 0; b < 4; b++) acc[a][b] = (f32x4){0.f,0.f,0.f,0.f};

  STAGE(0, 0);
  STAGE(1, 1);
  FENCE_VM3;
  BAR;

  int p = 0, p2 = 2;
  for (int kt = 0; kt < 32; ++kt){
    if (kt <= 29) STAGE(p2, kt + 2);

    s16x8 af[4], bf[4];
    #pragma unroll
    for (int ni = 0; ni < 4; ni++)
      bf[ni] = *reinterpret_cast<const s16x8*>(&Bs[p][(wc*64 + ni*16 + l15) * 32 + fs * 8]);
    #pragma unroll
    for (int mi = 0; mi < 4; mi++)
      if (mi < miN)
        af[mi] = *reinterpret_cast<const s16x8*>(&As[p][(wr*64 + mi*16 + l15) * 32 + fs * 8]);

    __builtin_amdgcn_s_setprio(1);
    #pragma unroll
    for (int mi = 0; mi < 4; mi++)
      if (mi < miN)
        #pragma unroll
        for (int ni = 0; ni < 4; ni++)
          acc[mi][ni] = __builtin_amdgcn_mfma_f32_16x16x32_bf16(af[mi], bf[ni], acc[mi][ni], 0, 0, 0);
    __builtin_amdgcn_s_setprio(0);

    if (kt < 31){
      if (kt <= 29) FENCE_VM3;
      else          FENCE_VM0;
      BAR;
    }
    p  = (p  == 2) ? 0 : p  + 1;
    p2 = (p2 == 2) ? 0 : p2 + 1;
  }
  #undef STAGE

  const bool isQ = (tx < 4);
  ushort_t* outp; int ostride, col0;
  if (tx < 4)      { outp = Qb;  ostride = 1024; col0 = tx * 256; }
  else if (tx < 8) { outp = KVb; ostride = 2048; col0 = (tx - 4) * 256; }
  else             { outp = KVb; ostride = 2048; col0 = 1024 + (tx - 8) * 256; }

  #pragma unroll
  for (int mi = 0; mi < 4; mi++){
    #pragma unroll
    for (int r2 = 0; r2 < 4; r2++){
      const int gm = m0 + wr*64 + mi*16 + lg*4 + r2;
      if (gm < BROWS){
        const float rsv = isQ ? rs[gm] : 0.f;
        const float muv = isQ ? mu[gm] : 0.f;
        #pragma unroll
        for (int ni = 0; ni < 4; ni++){
          const int nl = wc*64 + ni*16 + l15;
          float v = acc[mi][ni][r2];
          if (isQ) v = 0.125f * (rsv * (v - muv * cg[tx*256 + nl]) + cb[tx*256 + nl]);
          outp[(size_t)gm * ostride + col0 + nl] = f2bf(v);
        }
      }
    }
  }
}

// ---------------------------------------------------------------- FC GEMM (r7-proven)
// out = ctx @ Wfc + bias + resid. BM=64, BN=128, 3-buffer counted vmcnt(3).
__global__ __launch_bounds__(256) void fc_gemm(const ushort_t* __restrict__ A,
    const ushort_t* __restrict__ Bt, const float* __restrict__ bias,
    const float* __restrict__ resid, float* __restrict__ out){
  __shared__ __align__(16) ushort_t Asf[3][64 * 32];   // 12 KB
  __shared__ __align__(16) ushort_t Bsf[3][128 * 32];  // 24 KB
  const int tid = threadIdx.x;
  const int w = tid >> 6, lane = tid & 63;
  const int l15 = lane & 15, lg = lane >> 4;
  const int wr = w >> 1, wc = w & 1;

  const int bswz = ((int)blockIdx.x & 7) * 85 + ((int)blockIdx.x >> 3);   // 680 = 8*85
  const int ty = bswz >> 3, tx = bswz & 7;
  const int m0 = ty * 64, n0 = tx * 128;

  const int rch = lane >> 2, slot = lane & 3;
  const int gch = slot ^ ((rch >> 1) & 3);
  const ushort_t* a_src  = A  + (size_t)(m0 + w * 16 + rch) * DM + gch * 8;
  const ushort_t* b_src0 = Bt + (size_t)(n0 + w * 32      + rch) * DM + gch * 8;
  const ushort_t* b_src1 = Bt + (size_t)(n0 + w * 32 + 16 + rch) * DM + gch * 8;

  #define FSTAGE(P, T) do { \
    gload16(a_src  + (T) * 32, &Asf[P][(w * 16     ) * 32]); \
    gload16(b_src0 + (T) * 32, &Bsf[P][(w * 32     ) * 32]); \
    gload16(b_src1 + (T) * 32, &Bsf[P][(w * 32 + 16) * 32]); \
  } while(0)

  const int fs = lg ^ ((l15 >> 1) & 3);

  f32x4 acc[2][4];
  #pragma unroll
  for (int a = 0; a < 2; a++)
    #pragma unroll
    for (int b = 0; b < 4; b++) acc[a][b] = (f32x4){0.f,0.f,0.f,0.f};

  FSTAGE(0, 0);
  FSTAGE(1, 1);
  FENCE_VM3;
  BAR;

  int p = 0, p2 = 2;
  for (int kt = 0; kt < 32; ++kt){
    if (kt <= 29) FSTAGE(p2, kt + 2);

    s16x8 af[2], bf[4];
    #pragma unroll
    for (int mi = 0; mi < 2; mi++)
      af[mi] = *reinterpret_cast<const s16x8*>(&Asf[p][(wr*32 + mi*16 + l15) * 32 + fs * 8]);
    #pragma unroll
    for (int ni = 0; ni < 4; ni++)
      bf[ni] = *reinterpret_cast<const s16x8*>(&Bsf[p][(wc*64 + ni*16 + l15) * 32 + fs * 8]);
    #pragma unroll
    for (int mi = 0; mi < 2; mi++)
      #pragma unroll
      for (int ni = 0; ni < 4; ni++)
        acc[mi][ni] = __builtin_amdgcn_mfma_f32_16x16x32_bf16(af[mi], bf[ni], acc[mi][ni], 0, 0, 0);

    if (kt < 31){
      if (kt <= 29) FENCE_VM3;
      else          FENCE_VM0;
      BAR;
    }
    p  = (p  == 2) ? 0 : p  + 1;
    p2 = (p2 == 2) ? 0 : p2 + 1;
  }
  #undef FSTAGE

  #pragma unroll
  for (int mi = 0; mi < 2; mi++)
    #pragma unroll
    for (int ni = 0; ni < 4; ni++){
      const int gn = n0 + wc*64 + ni*16 + l15;
      #pragma unroll
      for (int r2 = 0; r2 < 4; r2++){
        const int gm = m0 + wr*32 + mi*16 + lg*4 + r2;
        out[(size_t)gm * DM + gn] = acc[mi][ni][r2] + bias[gn] + resid[(size_t)gm * DM + gn];
      }
    }
}

// ---------------------------------------------------------------- sparse PAM attention
__global__ __launch_bounds__(256) void attn_kernel(const ushort_t* __restrict__ Q,
    const ushort_t* __restrict__ KV, ushort_t* __restrict__ ctx){
  const int wid = threadIdx.x >> 6, lane = threadIdx.x & 63;
  const int gw = blockIdx.x * 4 + wid;
  const int b = gw / L_TOT;
  const int rem = gw - b * L_TOT;
  const int h = rem / 85;
  const int qt = rem - h * 85;
  const int l15 = lane & 15, g = lane >> 4;
  const int i = qt * 16 + l15;
  const int row = b * L_TOT + i;
  const int brow0 = b * L_TOT;

  int st, sz;
  if      (i < 1024){ st = 0;    sz = 1024; }
  else if (i < 1280){ st = 1024; sz = 256;  }
  else if (i < 1344){ st = 1280; sz = 64;   }
  else              { st = 1344; sz = 16;   }

  int key[10]; bool val[10];
  #pragma unroll
  for (int s = 0; s < 5; s++){
    int j = i - 2 + s;
    val[s] = (j >= st) && (j < st + sz);
    key[s] = val[s] ? j : i;
  }
  const bool haskid = (i >= 1024);
  const int cs = haskid ? (st - sz * 4 + (i - st) * 4) : i;
  #pragma unroll
  for (int c = 0; c < 4; c++){ key[5 + c] = haskid ? (cs + c) : i; val[5 + c] = haskid; }
  const bool haspar = (i < 1344);
  key[9] = haspar ? (st + sz + ((i - st) >> 2)) : i;
  val[9] = haspar;

  const int dcol = h * 64 + g * 16;
  const ushort_t* qp = Q + (size_t)row * DM + dcol;
  s16x8 q0 = *reinterpret_cast<const s16x8*>(qp);
  s16x8 q1 = *reinterpret_cast<const s16x8*>(qp + 8);
  float qf[16];
  #pragma unroll
  for (int j = 0; j < 8; j++){ qf[j] = b2f((ushort_t)q0[j]); qf[8 + j] = b2f((ushort_t)q1[j]); }

  size_t koff[10];
  float sc[10];
  #pragma unroll
  for (int s = 0; s < 10; s++){
    koff[s] = (size_t)(brow0 + key[s]) * 2048 + dcol;
    const ushort_t* kp = KV + koff[s];
    s16x8 k0 = *reinterpret_cast<const s16x8*>(kp);
    s16x8 k1 = *reinterpret_cast<const s16x8*>(kp + 8);
    float p = 0.f;
    #pragma unroll
    for (int j = 0; j < 8; j++){
      p += qf[j]     * b2f((ushort_t)k0[j]);
      p += qf[8 + j] * b2f((ushort_t)k1[j]);
    }
    p += __shfl_xor(p, 16);
    p += __shfl_xor(p, 32);
    sc[s] = val[s] ? p : -1e30f;
  }

  float m = sc[0];
  #pragma unroll
  for (int s = 1; s < 10; s++) m = fmaxf(m, sc[s]);
  float e[10]; float sum = 0.f;
  #pragma unroll
  for (int s = 0; s < 10; s++){ e[s] = __expf(sc[s] - m); sum += e[s]; }
  const float inv = 1.0f / sum;

  float accv[16];
  #pragma unroll
  for (int j = 0; j < 16; j++) accv[j] = 0.f;
  #pragma unroll
  for (int s = 0; s < 10; s++){
    const ushort_t* vp = KV + koff[s] + 1024;
    s16x8 v0 = *reinterpret_cast<const s16x8*>(vp);
    s16x8 v1 = *reinterpret_cast<const s16x8*>(vp + 8);
    const float w = e[s];
    #pragma unroll
    for (int j = 0; j < 8; j++){
      accv[j]     += w * b2f((ushort_t)v0[j]);
      accv[8 + j] += w * b2f((ushort_t)v1[j]);
    }
  }

  // sigma store (feeds fc_gemm staging)
  ushort_t* op = ctx + (size_t)row * DM + 32 * (2 * h + (g >> 1)) + 4 * (g & 1);
  #pragma unroll
  for (int m2 = 0; m2 < 4; m2++){
    uint2 o;
    o.x = cvtpk(accv[4*m2+0]*inv, accv[4*m2+1]*inv);
    o.y = cvtpk(accv[4*m2+2]*inv, accv[4*m2+3]*inv);
    *reinterpret_cast<uint2*>(op + 8 * m2) = o;
  }
}

// ---------------------------------------------------------------- launch
extern "C" void kernel_launch(void* const* d_in, const int* in_sizes, int n_in,
                              void* d_out, int out_size, void* d_ws, size_t ws_size,
                              hipStream_t stream){
  (void)in_sizes; (void)n_in; (void)out_size; (void)ws_size;
  const float* x     = (const float*)d_in[0];
  const float* Wq    = (const float*)d_in[1];
  const float* Wk    = (const float*)d_in[2];
  const float* Wv    = (const float*)d_in[3];
  const float* Wfc   = (const float*)d_in[4];
  const float* bfc   = (const float*)d_in[5];
  const float* gamma = (const float*)d_in[6];
  const float* beta  = (const float*)d_in[7];
  float* out = (float*)d_out;

  char* ws = (char*)d_ws;
  const size_t SLAB = (size_t)BROWS * DM * sizeof(ushort_t);   // 11,141,120 B
  ushort_t* Wqkv_t = (ushort_t*)(ws);                           // 6 MB (sigma)
  ushort_t* Wfc_t  = (ushort_t*)(ws + 6291456);                 // 2 MB (sigma)
  float*    cg     = (float*)(ws + 8388608);
  float*    cb     = (float*)(ws + 8392704);
  float*    muv    = (float*)(ws + 8396800);
  float*    rsv    = (float*)(ws + 8418560);
  ushort_t* Qb  = (ushort_t*)(ws + SLAB);       // Q -> ctx (in place, ctx sigma)
  ushort_t* ctx = Qb;
  ushort_t* KVb = (ushort_t*)(ws + 2 * SLAB);   // [row][K|V] stride 2048
  ushort_t* x_bf = (ushort_t*)(ws + 4 * SLAB);  // x bf16, sigma

  prep_kernel<<<2448, 256, 0, stream>>>(x, Wq, Wk, Wv, Wfc, gamma, beta,
      muv, rsv, x_bf, cg, cb, Wqkv_t, Wfc_t);
  qkv_gemm<<<516, 512, 0, stream>>>(x_bf, Wqkv_t, Qb, KVb, cg, cb, muv, rsv);
  attn_kernel<<<L_TOT, 256, 0, stream>>>(Qb, KVb, ctx);
  fc_gemm<<<680, 256, 0, stream>>>(ctx, Wfc_t, bfc, x, out);
}